// Round 9
// baseline (879.840 us; speedup 1.0000x reference)
//
#include <hip/hip_runtime.h>

#define T_ 3
#define NPER 20000
#define NN 60000
#define EE 480000
#define BB 200000
#define RR 5
#define NT 3130    // BB/64 + RR  (padded pair tiles)
#define TILESN 938 // ceil(NN/64)
#define TILEST 313 // ceil(NPER/64)

__device__ inline float lrelu(float x){ return x > 0.f ? x : 0.2f*x; }
__device__ inline float eluf(float x){ return x > 0.f ? x : (__expf(x) - 1.f); }
__device__ inline void fma4(float4& a, float s, const float4 v){ a.x+=s*v.x; a.y+=s*v.y; a.z+=s*v.z; a.w+=s*v.w; }
// bf16 helpers (RNE pack; unpack is shift/mask)
__device__ inline unsigned short f2b(float f){
    unsigned u = __float_as_uint(f);
    u = u + 0x7FFFu + ((u >> 16) & 1u);
    return (unsigned short)(u >> 16);
}
__device__ inline float bs2f(unsigned short b){ return __uint_as_float(((unsigned)b) << 16); }
__device__ inline float b2lo(unsigned u){ return __uint_as_float(u << 16); }
__device__ inline float b2hi(unsigned u){ return __uint_as_float(u & 0xFFFF0000u); }

// ---- combine input-fc with layer0 weights: cw[t]=fcw[t]@w0[t] [64x64], cb[t]=fcb[t]@w0[t] ----
__global__ __launch_bounds__(256) void k_combine(const float* __restrict__ fcw,
        const float* __restrict__ fcb, const float* __restrict__ w0,
        float* __restrict__ cw, float* __restrict__ cb) {
    __shared__ float A[64*32];
    __shared__ float Bm[32*64];
    int t = blockIdx.x, tid = threadIdx.x;
    for (int e = tid; e < 2048; e += 256) { A[e] = fcw[t*2048 + e]; Bm[e] = w0[t*2048 + e]; }
    __syncthreads();
    for (int e = tid; e < 4096; e += 256) {
        int k = e >> 6, o = e & 63;
        float acc = 0.f;
        #pragma unroll
        for (int m = 0; m < 32; ++m) acc += A[k*32+m] * Bm[m*64+o];
        cw[t*4096 + e] = acc;
    }
    if (tid < 64) {
        float acc = 0.f;
        #pragma unroll
        for (int m = 0; m < 32; ++m) acc += fcb[t*32+m] * Bm[m*64+tid];
        cb[t*64 + tid] = acc;
    }
}

// ---- fused input-fc + emb0 ----
__global__ __launch_bounds__(256) void k_ntz(const float* __restrict__ feats,
        const float* __restrict__ fcw, const float* __restrict__ fcb,
        float* __restrict__ z) {
    __shared__ float Xs[64][65];
    __shared__ float Ws[64*32];
    __shared__ float nrS[64];
    int ty = blockIdx.y;
    int n0 = ty*NPER + blockIdx.x*64;
    int nmax = (ty+1)*NPER;
    int tid = threadIdx.x;
    for (int e = tid; e < 4096; e += 256) {
        int n = e >> 6, k = e & 63;
        int gn = n0 + n;
        Xs[n][k] = (gn < nmax) ? feats[(size_t)gn*64 + k] : 0.f;
    }
    for (int e = tid; e < 2048; e += 256) Ws[e] = fcw[ty*2048 + e];
    __syncthreads();
    int ix = tid & 15, iy = tid >> 4;
    float acc[4][2] = {};
    #pragma unroll 8
    for (int k = 0; k < 64; ++k) {
        float wa = Ws[k*32 + 2*iy], wb = Ws[k*32 + 2*iy + 1];
        #pragma unroll
        for (int p = 0; p < 4; ++p) {
            float x = Xs[ix*4+p][k];
            acc[p][0] += x*wa; acc[p][1] += x*wb;
        }
    }
    float ba = fcb[ty*32 + 2*iy], bb = fcb[ty*32 + 2*iy + 1];
    __syncthreads();
    #pragma unroll
    for (int p = 0; p < 4; ++p) {
        acc[p][0] += ba; acc[p][1] += bb;
        Xs[ix*4+p][2*iy] = acc[p][0]; Xs[ix*4+p][2*iy+1] = acc[p][1];
    }
    __syncthreads();
    if (tid < 64) {
        float ss = 0.f;
        #pragma unroll
        for (int c = 0; c < 32; ++c) { float v = Xs[tid][c]; ss += v*v; }
        nrS[tid] = 3.f * fmaxf(sqrtf(ss), 1e-12f);
    }
    __syncthreads();
    #pragma unroll
    for (int p = 0; p < 4; ++p) {
        int gn = n0 + ix*4 + p;
        if (gn < nmax) {
            float inv = 1.f / nrS[ix*4+p];
            z[(size_t)gn*128 + 2*iy]   = acc[p][0]*inv;
            z[(size_t)gn*128 + 2*iy+1] = acc[p][1]*inv;
        }
    }
}

// ---- layer0 feat (GEMM-tiled, f32 out) + el/er epilogue ----
__global__ __launch_bounds__(256) void k_f0t(const float* __restrict__ feats,
        const float* __restrict__ cw, const float* __restrict__ cb,
        const float* __restrict__ al, const float* __restrict__ ar,
        float* __restrict__ f0, float* __restrict__ el, float* __restrict__ er) {
    __shared__ float Xs[64][65];
    __shared__ float Ws[64*64];
    __shared__ float avec[2][32], rvec[2][32];
    int ty = blockIdx.y;
    int n0 = ty*NPER + blockIdx.x*64;
    int nmax = (ty+1)*NPER;
    int tid = threadIdx.x;
    for (int e = tid; e < 4096; e += 256) {
        int n = e >> 6, k = e & 63;
        int gn = n0 + n;
        Xs[n][k] = (gn < nmax) ? feats[(size_t)gn*64 + k] : 0.f;
        Ws[e] = cw[ty*4096 + e];
    }
    if (tid < 64) {
        avec[tid>>5][tid&31] = al[(tid>>5)*96 + ty*32 + (tid&31)];
        rvec[tid>>5][tid&31] = ar[(tid>>5)*96 + ty*32 + (tid&31)];
    }
    __syncthreads();
    int ix = tid & 15, iy = tid >> 4;
    float acc[4][4] = {};
    #pragma unroll 8
    for (int k = 0; k < 64; ++k) {
        float4 wv = *(const float4*)&Ws[k*64 + iy*4];
        #pragma unroll
        for (int p = 0; p < 4; ++p) {
            float x = Xs[ix*4+p][k];
            acc[p][0] += x*wv.x; acc[p][1] += x*wv.y; acc[p][2] += x*wv.z; acc[p][3] += x*wv.w;
        }
    }
    float b0v = cb[ty*64 + iy*4], b1v = cb[ty*64 + iy*4+1], b2v = cb[ty*64 + iy*4+2], b3v = cb[ty*64 + iy*4+3];
    __syncthreads();
    #pragma unroll
    for (int p = 0; p < 4; ++p) {
        acc[p][0] += b0v; acc[p][1] += b1v; acc[p][2] += b2v; acc[p][3] += b3v;
        Xs[ix*4+p][iy*4]   = acc[p][0];
        Xs[ix*4+p][iy*4+1] = acc[p][1];
        Xs[ix*4+p][iy*4+2] = acc[p][2];
        Xs[ix*4+p][iy*4+3] = acc[p][3];
    }
    #pragma unroll
    for (int p = 0; p < 4; ++p) {
        int gn = n0 + ix*4 + p;
        if (gn < nmax)
            *(float4*)&f0[(size_t)gn*64 + iy*4] = make_float4(acc[p][0],acc[p][1],acc[p][2],acc[p][3]);
    }
    __syncthreads();
    if (tid < 128) {
        int n = tid >> 1, h = tid & 1;
        int gn = n0 + n;
        float pe = 0.f, pr = 0.f;
        #pragma unroll
        for (int d = 0; d < 32; ++d) {
            float v = Xs[n][h*32+d];
            pe += v*avec[h][d]; pr += v*rvec[h][d];
        }
        if (gn < nmax) { el[gn*2+h] = pe; er[gn*2+h] = pr; }
    }
}

// ---- layer1 feat (GEMM-tiled per slot t) -> bf16 out ----
__global__ __launch_bounds__(256) void k_f1t(const float* __restrict__ h1,
        const float* __restrict__ w1, unsigned short* __restrict__ f1) {
    __shared__ float Xs[64][65];
    __shared__ float Ws[64*64];
    int t = blockIdx.y;
    int n0 = blockIdx.x*64;
    int tid = threadIdx.x;
    for (int e = tid; e < 4096; e += 256) {
        int n = e >> 6, k = e & 63;
        int gn = n0 + n;
        Xs[n][k] = (gn < NN) ? h1[(size_t)gn*192 + (k>>5)*96 + t*32 + (k&31)] : 0.f;
        Ws[e] = w1[t*4096 + e];
    }
    __syncthreads();
    int ix = tid & 15, iy = tid >> 4;
    float acc[4][4] = {};
    #pragma unroll 8
    for (int k = 0; k < 64; ++k) {
        float4 wv = *(const float4*)&Ws[k*64 + iy*4];
        #pragma unroll
        for (int p = 0; p < 4; ++p) {
            float x = Xs[ix*4+p][k];
            acc[p][0] += x*wv.x; acc[p][1] += x*wv.y; acc[p][2] += x*wv.z; acc[p][3] += x*wv.w;
        }
    }
    int h = iy >> 3, dd = (iy & 7)*4;
    #pragma unroll
    for (int p = 0; p < 4; ++p) {
        int gn = n0 + ix*4 + p;
        if (gn < NN) {
            ushort4 o;
            o.x = f2b(acc[p][0]); o.y = f2b(acc[p][1]); o.z = f2b(acc[p][2]); o.w = f2b(acc[p][3]);
            *(ushort4*)&f1[(size_t)gn*192 + h*96 + t*32 + dd] = o;
        }
    }
}

// ---- layer2 feat (bf16) + residual (f32) ----
__global__ __launch_bounds__(256) void k_f2t(const float* __restrict__ h2,
        const float* __restrict__ w2, const float* __restrict__ rw,
        unsigned short* __restrict__ f2, float* __restrict__ rst2) {
    __shared__ float Xs[64][65];
    __shared__ float Ws[64*64];
    int t = blockIdx.y;
    int n0 = blockIdx.x*64;
    int tid = threadIdx.x;
    for (int e = tid; e < 4096; e += 256) {
        int n = e >> 6, k = e & 63;
        int gn = n0 + n;
        Xs[n][k] = (gn < NN) ? h2[(size_t)gn*192 + (k>>5)*96 + t*32 + (k&31)] : 0.f;
        int c = e & 63;
        Ws[e] = (c < 32) ? w2[t*2048 + n*32 + c] : rw[n*32 + (c-32)];
    }
    __syncthreads();
    int ix = tid & 15, iy = tid >> 4;
    float acc[4][4] = {};
    #pragma unroll 8
    for (int k = 0; k < 64; ++k) {
        float4 wv = *(const float4*)&Ws[k*64 + iy*4];
        #pragma unroll
        for (int p = 0; p < 4; ++p) {
            float x = Xs[ix*4+p][k];
            acc[p][0] += x*wv.x; acc[p][1] += x*wv.y; acc[p][2] += x*wv.z; acc[p][3] += x*wv.w;
        }
    }
    #pragma unroll
    for (int p = 0; p < 4; ++p) {
        int gn = n0 + ix*4 + p;
        if (gn < NN) {
            if (iy < 8) {
                ushort4 o;
                o.x = f2b(acc[p][0]); o.y = f2b(acc[p][1]); o.z = f2b(acc[p][2]); o.w = f2b(acc[p][3]);
                *(ushort4*)&f2[(size_t)gn*96 + t*32 + iy*4] = o;
            } else {
                *(float4*)&rst2[(size_t)gn*96 + t*32 + (iy-8)*4] = make_float4(acc[p][0],acc[p][1],acc[p][2],acc[p][3]);
            }
        }
    }
}

// ---- CSR build ----
__global__ void k_deg(const int* __restrict__ dst, int* __restrict__ deg) {
    int e = blockIdx.x*256 + threadIdx.x;
    if (e < EE) atomicAdd(&deg[dst[e]], 1);
}

__global__ __launch_bounds__(1024) void k_scan(const int* __restrict__ deg, int* __restrict__ rowptr) {
    __shared__ int sbase;
    __shared__ int wsum[16];
    int tid = threadIdx.x;
    if (tid == 0) sbase = 0;
    __syncthreads();
    for (int c0 = 0; c0 < NN; c0 += 1024) {
        int i = c0 + tid;
        int v = (i < NN) ? deg[i] : 0;
        int x = v;
        for (int d = 1; d < 64; d <<= 1) { int y = __shfl_up(x, d, 64); if ((tid & 63) >= d) x += y; }
        if ((tid & 63) == 63) wsum[tid >> 6] = x;
        __syncthreads();
        if (tid < 16) { int w = wsum[tid];
            for (int d = 1; d < 16; d <<= 1) { int y = __shfl_up(w, d, 64); if (tid >= d) w += y; }
            wsum[tid] = w; }
        __syncthreads();
        int woff = (tid >> 6) == 0 ? 0 : wsum[(tid >> 6) - 1];
        int incl = x + woff;
        if (i < NN) rowptr[i] = sbase + incl - v;
        __syncthreads();
        if (tid == 1023) sbase += incl;
        __syncthreads();
    }
    if (tid == 0) rowptr[NN] = sbase;
}

__global__ void k_fill(const int* __restrict__ dst, const int* __restrict__ rowptr,
                       int* __restrict__ cursor, int* __restrict__ eidx) {
    int e = blockIdx.x*256 + threadIdx.x;
    if (e >= EE) return;
    int d = dst[e];
    int pos = atomicAdd(&cursor[d], 1);
    eidx[rowptr[d] + pos] = e;
}

// ---- pair bucketing ----
__global__ __launch_bounds__(256) void k_bcnt(const int* __restrict__ mid, int* __restrict__ cnt) {
    __shared__ int h[RR];
    int tid = threadIdx.x, lane = tid & 63;
    if (tid < RR) h[tid] = 0;
    __syncthreads();
    int b = blockIdx.x*256 + tid;
    int r = (b < BB) ? mid[b] : -1;
    #pragma unroll
    for (int rr = 0; rr < RR; ++rr) {
        unsigned long long m = __ballot(r == rr);
        if (lane == 0 && m) atomicAdd(&h[rr], (int)__popcll(m));
    }
    __syncthreads();
    if (tid < RR && h[tid]) atomicAdd(&cnt[tid], h[tid]);
}

__global__ void k_bscan(const int* __restrict__ cnt, int* __restrict__ base) {
    base[0] = 0;
    for (int r = 0; r < RR; ++r) base[r+1] = base[r] + (((cnt[r] + 63) >> 6) << 6);
}

__global__ __launch_bounds__(256) void k_bfill(const int* __restrict__ mid, const int* __restrict__ base,
                        int* __restrict__ gcur, int* __restrict__ perm) {
    __shared__ int wcnt[4][RR];
    __shared__ int wbase[4][RR];
    __shared__ int bbase[RR];
    int tid = threadIdx.x, w = tid >> 6, lane = tid & 63;
    int b = blockIdx.x*256 + tid;
    int r = (b < BB) ? mid[b] : -1;
    int myrank = 0;
    #pragma unroll
    for (int rr = 0; rr < RR; ++rr) {
        unsigned long long m = __ballot(r == rr);
        if (r == rr) myrank = (int)__popcll(m & ((1ull << lane) - 1ull));
        if (lane == 0) wcnt[w][rr] = (int)__popcll(m);
    }
    __syncthreads();
    if (tid < RR) {
        int s = 0;
        #pragma unroll
        for (int ww = 0; ww < 4; ++ww) { wbase[ww][tid] = s; s += wcnt[ww][tid]; }
        bbase[tid] = s ? atomicAdd(&gcur[tid], s) : 0;
    }
    __syncthreads();
    if (r >= 0) perm[base[r] + bbase[r] + wbase[w][r] + myrank] = b;
}

// ---- edge logit table ----
__global__ void k_tab(const float* __restrict__ eemb, const float* __restrict__ fcw,
                      const float* __restrict__ fcb, const float* __restrict__ ae,
                      int H, float* __restrict__ tab) {
    int r = blockIdx.x / H, h = blockIdx.x % H, d = threadIdx.x;
    float acc = fcb[h*64+d];
    const float* er = eemb + r*64;
    #pragma unroll
    for (int k = 0; k < 64; ++k) acc += er[k] * fcw[k*(H*64) + h*64 + d];
    float v = acc * ae[h*64+d];
    for (int off = 32; off; off >>= 1) v += __shfl_xor(v, off, 64);
    if (d == 0) tab[r*H+h] = v;
}

// ---- fused per-node softmax + gather-aggregate + finalize ----
// MODE 0: H=2, f f32 [N,64] slot-compact; MODE 1: H=2, f bf16 [N,192]; MODE 2: H=1, f bf16 [N,96]
// deg<=128 fast path: logits computed ONCE into registers (<=2 edges/lane), a written straight to s_a.
template<int MODE, int H>
__global__ __launch_bounds__(192) void k_aggr(
        const int* __restrict__ rowptr, const int* __restrict__ eidx,
        const int* __restrict__ src, const int* __restrict__ et,
        const float* __restrict__ el, const float* __restrict__ er,
        const float* __restrict__ tab, const void* __restrict__ fv,
        const float* __restrict__ resat, float* __restrict__ store0,
        const float* __restrict__ resid, const float* __restrict__ bias,
        float* __restrict__ outp, float* __restrict__ z, int zc) {
    constexpr int COLS  = (MODE==0) ? 64 : (MODE==1) ? 192 : 96;
    constexpr int PER   = (MODE==0) ? 4 : 8;
    constexpr int LANES = COLS/PER;           // 16 / 24 / 12
    constexpr int G     = 192/LANES;          // 12 / 8  / 16
    constexpr int RCOLS = (MODE==0) ? 192 : COLS;
    __shared__ float s_a[128][2];
    __shared__ int s_src[128];
    __shared__ int s_ts[128];
    __shared__ __align__(16) float red[G][RCOLS];
    __shared__ float hs[192];
    __shared__ float xs[96];
    __shared__ float part[2];
    int n = blockIdx.x, tid = threadIdx.x;
    int e0 = rowptr[n];
    int deg = rowptr[n+1] - e0;
    bool fast = (deg <= 128);
    float m0 = -1e30f, m1 = -1e30f, sum0 = 0.f, sum1 = 0.f;
    float er0 = 0.f, er1 = 0.f;
    if (tid < 64) {
        er0 = er[n*H];
        if (H == 2) er1 = er[n*H+1];
        if (fast) {
            int eA = 0, sA = 0, eB = 0, sB = 0;
            float xA0 = 0.f, xA1 = 0.f, xB0 = 0.f, xB1 = 0.f;
            bool hA = tid < deg, hB = tid + 64 < deg;
            if (hA) {
                eA = eidx[e0+tid]; sA = src[eA]; int rr = et[eA];
                xA0 = lrelu(el[sA*H] + er0 + tab[rr*H]);
                m0 = xA0;
                if (H == 2) { xA1 = lrelu(el[sA*H+1] + er1 + tab[rr*H+1]); m1 = xA1; }
            }
            if (hB) {
                eB = eidx[e0+tid+64]; sB = src[eB]; int rr = et[eB];
                xB0 = lrelu(el[sB*H] + er0 + tab[rr*H]);
                m0 = fmaxf(m0, xB0);
                if (H == 2) { xB1 = lrelu(el[sB*H+1] + er1 + tab[rr*H+1]); m1 = fmaxf(m1, xB1); }
            }
            for (int off = 32; off; off >>= 1) {
                m0 = fmaxf(m0, __shfl_xor(m0, off, 64));
                if (H == 2) m1 = fmaxf(m1, __shfl_xor(m1, off, 64));
            }
            float exA0 = 0.f, exA1 = 0.f, exB0 = 0.f, exB1 = 0.f;
            if (hA) { exA0 = __expf(xA0 - m0); sum0 += exA0;
                      if (H == 2) { exA1 = __expf(xA1 - m1); sum1 += exA1; } }
            if (hB) { exB0 = __expf(xB0 - m0); sum0 += exB0;
                      if (H == 2) { exB1 = __expf(xB1 - m1); sum1 += exB1; } }
            for (int off = 32; off; off >>= 1) {
                sum0 += __shfl_xor(sum0, off, 64);
                if (H == 2) sum1 += __shfl_xor(sum1, off, 64);
            }
            if (hA) {
                float a0 = exA0 / (sum0 + 1e-9f);
                if (MODE == 1) a0 = a0*0.95f + resat[eA*2]*0.05f;
                if (MODE == 0) store0[eA*2] = a0;
                s_a[tid][0] = a0;
                if (H == 2) {
                    float a1 = exA1 / (sum1 + 1e-9f);
                    if (MODE == 1) a1 = a1*0.95f + resat[eA*2+1]*0.05f;
                    if (MODE == 0) store0[eA*2+1] = a1;
                    s_a[tid][1] = a1;
                }
                s_src[tid] = sA;
                if (MODE == 0) s_ts[tid] = sA / NPER;
            }
            if (hB) {
                float a0 = exB0 / (sum0 + 1e-9f);
                if (MODE == 1) a0 = a0*0.95f + resat[eB*2]*0.05f;
                if (MODE == 0) store0[eB*2] = a0;
                s_a[tid+64][0] = a0;
                if (H == 2) {
                    float a1 = exB1 / (sum1 + 1e-9f);
                    if (MODE == 1) a1 = a1*0.95f + resat[eB*2+1]*0.05f;
                    if (MODE == 0) store0[eB*2+1] = a1;
                    s_a[tid+64][1] = a1;
                }
                s_src[tid+64] = sB;
                if (MODE == 0) s_ts[tid+64] = sB / NPER;
            }
        } else {
            for (int s2 = tid; s2 < deg; s2 += 64) {
                int e = eidx[e0+s2]; int sN = src[e]; int rr = et[e];
                float x0 = lrelu(el[sN*H] + er0 + tab[rr*H]);
                m0 = fmaxf(m0, x0);
                if (H == 2) { float x1 = lrelu(el[sN*H+1] + er1 + tab[rr*H+1]); m1 = fmaxf(m1, x1); }
            }
            for (int off = 32; off; off >>= 1) {
                m0 = fmaxf(m0, __shfl_xor(m0, off, 64));
                if (H == 2) m1 = fmaxf(m1, __shfl_xor(m1, off, 64));
            }
            for (int s2 = tid; s2 < deg; s2 += 64) {
                int e = eidx[e0+s2]; int sN = src[e]; int rr = et[e];
                float x0 = lrelu(el[sN*H] + er0 + tab[rr*H]);
                sum0 += __expf(x0 - m0);
                if (H == 2) { float x1 = lrelu(el[sN*H+1] + er1 + tab[rr*H+1]); sum1 += __expf(x1 - m1); }
            }
            for (int off = 32; off; off >>= 1) {
                sum0 += __shfl_xor(sum0, off, 64);
                if (H == 2) sum1 += __shfl_xor(sum1, off, 64);
            }
        }
    }
    float4 a0 = {0,0,0,0}, a1 = {0,0,0,0}, a2 = {0,0,0,0};
    int g = tid / LANES;
    int col = (tid - g*LANES)*PER;
    int hcol = (MODE==0) ? (col >> 5) : (MODE==1) ? (col / 96) : 0;
    for (int c0 = 0; c0 < deg; c0 += 128) {
        int cl = min(128, deg - c0);
        if (!fast && tid < 64) {
            for (int s2 = tid; s2 < cl; s2 += 64) {
                int e = eidx[e0+c0+s2]; int sN = src[e]; int rr = et[e];
                float x0 = lrelu(el[sN*H] + er0 + tab[rr*H]);
                float aa0 = __expf(x0 - m0) / (sum0 + 1e-9f);
                if (MODE == 1) aa0 = aa0*0.95f + resat[e*2]*0.05f;
                if (MODE == 0) store0[e*2] = aa0;
                s_a[s2][0] = aa0;
                if (H == 2) {
                    float x1 = lrelu(el[sN*H+1] + er1 + tab[rr*H+1]);
                    float aa1 = __expf(x1 - m1) / (sum1 + 1e-9f);
                    if (MODE == 1) aa1 = aa1*0.95f + resat[e*2+1]*0.05f;
                    if (MODE == 0) store0[e*2+1] = aa1;
                    s_a[s2][1] = aa1;
                }
                s_src[s2] = sN;
                if (MODE == 0) s_ts[s2] = sN / NPER;
            }
        }
        __syncthreads();
        if (MODE == 0) {
            const float* ff = (const float*)fv;
            for (int s2 = g; s2 < cl; s2 += G) {
                int sN = s_src[s2];
                float a = s_a[s2][hcol];
                float4 v = *(const float4*)&ff[(size_t)sN*64 + col];
                int ts = s_ts[s2];
                fma4(a0, (ts==0)?a:0.f, v);
                fma4(a1, (ts==1)?a:0.f, v);
                fma4(a2, (ts==2)?a:0.f, v);
            }
        } else {
            const unsigned short* fb = (const unsigned short*)fv;
            for (int s2 = g; s2 < cl; s2 += G) {
                int sN = s_src[s2];
                float a = s_a[s2][hcol];
                uint4 v = *(const uint4*)&fb[(size_t)sN*COLS + col];
                a0.x += a*b2lo(v.x); a0.y += a*b2hi(v.x);
                a0.z += a*b2lo(v.y); a0.w += a*b2hi(v.y);
                a1.x += a*b2lo(v.z); a1.y += a*b2hi(v.z);
                a1.z += a*b2lo(v.w); a1.w += a*b2hi(v.w);
            }
        }
        __syncthreads();
    }
    if (MODE == 0) {
        *(float4*)&red[g][col]       = a0;
        *(float4*)&red[g][64 + col]  = a1;
        *(float4*)&red[g][128 + col] = a2;
    } else {
        *(float4*)&red[g][col]     = a0;
        *(float4*)&red[g][col + 4] = a1;
    }
    __syncthreads();
    constexpr int FC = (MODE==2) ? 96 : 192;
    if (tid < FC) {
        int rc;
        if (MODE == 0) { int hh = tid/96, km = tid - hh*96, t = km>>5, d = km&31; rc = t*64 + hh*32 + d; }
        else rc = tid;
        float val = 0.f;
        #pragma unroll
        for (int gg = 0; gg < G; ++gg) val += red[gg][rc];
        if (MODE == 0) val = eluf(val + bias[tid]);
        if (MODE == 1) val = eluf(val + resid[(size_t)n*192 + tid] + bias[tid]);
        if (MODE == 2) val = val + resid[(size_t)n*96 + tid] + bias[tid];
        if (MODE < 2) outp[(size_t)n*192 + tid] = val;
        hs[tid] = val;
    }
    __syncthreads();
    float xx = 0.f;
    if (tid < 96) {
        float x = (MODE==2) ? hs[tid] : 0.5f*(hs[tid] + hs[96+tid]);
        xs[tid] = x;
        xx = x*x;
    }
    float s = xx;
    for (int off = 32; off; off >>= 1) s += __shfl_xor(s, off, 64);
    if ((tid & 63) == 0 && tid < 128) part[tid>>6] = s;
    __syncthreads();
    if (tid < 32) {
        float nr = 3.f * fmaxf(sqrtf(part[0] + part[1]), 1e-12f);
        z[(size_t)n*128 + zc + tid] = (xs[tid] + xs[32+tid] + xs[64+tid]) / nr;
    }
}

// ---- el/er for layer1 (bf16 f1) ----
__global__ void k_el1(const unsigned short* __restrict__ f1, const float* __restrict__ al,
                      const float* __restrict__ ar, float* __restrict__ el, float* __restrict__ er) {
    int gid = blockIdx.x*256 + threadIdx.x;
    int n = gid >> 6, l = gid & 63;
    if (n >= NN) return;
    const unsigned short* b = f1 + (size_t)n*192;
    float v0 = bs2f(b[l]), v1 = bs2f(b[l+64]), v2 = bs2f(b[l+128]);
    float pe0 = v0*al[l],     pr0 = v0*ar[l];
    float pe1 = v2*al[l+128], pr1 = v2*ar[l+128];
    float me = v1*al[l+64], mr = v1*ar[l+64];
    if (l < 32) { pe0 += me; pr0 += mr; } else { pe1 += me; pr1 += mr; }
    for (int off = 32; off; off >>= 1) {
        pe0 += __shfl_xor(pe0, off, 64); pr0 += __shfl_xor(pr0, off, 64);
        pe1 += __shfl_xor(pe1, off, 64); pr1 += __shfl_xor(pr1, off, 64);
    }
    if (l == 0) { el[n*2] = pe0; el[n*2+1] = pe1; er[n*2] = pr0; er[n*2+1] = pr1; }
}

// ---- el/er for layer2 (bf16 f2) ----
__global__ void k_el2(const unsigned short* __restrict__ f2, const float* __restrict__ al,
                      const float* __restrict__ ar, float* __restrict__ el, float* __restrict__ er) {
    int gid = blockIdx.x*256 + threadIdx.x;
    int n = gid >> 6, l = gid & 63;
    if (n >= NN) return;
    const unsigned short* b = f2 + (size_t)n*96;
    float v0 = bs2f(b[l]);
    float pe = v0*al[l], pr = v0*ar[l];
    if (l < 32) { float v1 = bs2f(b[64+l]); pe += v1*al[64+l]; pr += v1*ar[64+l]; }
    for (int off = 32; off; off >>= 1) { pe += __shfl_xor(pe, off, 64); pr += __shfl_xor(pr, off, 64); }
    if (l == 0) { el[n] = pe; er[n] = pr; }
}

// ---- DistMult v5: bf16 LDS operands, 8 pairs x 8 cols/thread, 2x ds_read_b128 per kk ----
// 128 threads: tx=tid&15 (8-col group), ty=tid>>4 in [0,8) (8-pair group). fp32 accumulate.
__global__ __launch_bounds__(128) void k_dm5(const float* __restrict__ z, const float* __restrict__ W,
                       const int* __restrict__ left, const int* __restrict__ right,
                       const int* __restrict__ mid, const int* __restrict__ perm,
                       float* __restrict__ out) {
    __shared__ unsigned short leT[128][72];               // [k][pair] bf16; row=144B (16B-aligned)
    __shared__ __align__(16) unsigned short w_s[16][128]; // [kk][col] bf16; 4KB chunk
    __shared__ int s_b[64], s_l[64], s_r[64];
    int tid = threadIdx.x;
    if (tid < 64) {
        int b = perm[blockIdx.x*64 + tid];
        s_b[tid] = b;
        s_l[tid] = (b >= 0) ? left[b]  : 0;
        s_r[tid] = (b >= 0) ? right[b] : 0;
    }
    __syncthreads();
    if (s_b[0] < 0) return;
    int r = mid[s_b[0]];
    // stage le^T bf16 (global coalesced; one-time LDS b16 writes)
    for (int i = tid; i < 8192; i += 128) {
        int p = i >> 7, c = i & 127;
        leT[c][p] = f2b(z[(size_t)s_l[p]*128 + c]);
    }
    const float* Wp = W + (size_t)r*16384;
    int tx = tid & 15, ty = tid >> 4;
    float acc[8][8] = {};
    for (int k0 = 0; k0 < 128; k0 += 16) {
        __syncthreads();
        for (int i = tid; i < 2048; i += 128) {
            int kk = i >> 7, c = i & 127;
            w_s[kk][c] = f2b(Wp[(size_t)(k0+kk)*128 + c]);
        }
        __syncthreads();
        #pragma unroll 4
        for (int kk = 0; kk < 16; ++kk) {
            uint4 wv = *(const uint4*)&w_s[kk][tx*8];         // 8 bf16 cols, 1 b128
            uint4 lv = *(const uint4*)&leT[k0+kk][ty*8];      // 8 bf16 pairs, 1 b128
            float ww[8] = { b2lo(wv.x), b2hi(wv.x), b2lo(wv.y), b2hi(wv.y),
                            b2lo(wv.z), b2hi(wv.z), b2lo(wv.w), b2hi(wv.w) };
            float lw[8] = { b2lo(lv.x), b2hi(lv.x), b2lo(lv.y), b2hi(lv.y),
                            b2lo(lv.z), b2hi(lv.z), b2lo(lv.w), b2hi(lv.w) };
            #pragma unroll
            for (int pp = 0; pp < 8; ++pp)
                #pragma unroll
                for (int jj = 0; jj < 8; ++jj)
                    acc[pp][jj] += lw[pp]*ww[jj];
        }
    }
    #pragma unroll
    for (int pp = 0; pp < 8; ++pp) {
        int p = ty*8 + pp;
        const float* zr = z + (size_t)s_r[p]*128;
        float4 rA = *(const float4*)&zr[tx*8];
        float4 rB = *(const float4*)&zr[tx*8 + 4];
        float part = acc[pp][0]*rA.x + acc[pp][1]*rA.y + acc[pp][2]*rA.z + acc[pp][3]*rA.w
                   + acc[pp][4]*rB.x + acc[pp][5]*rB.y + acc[pp][6]*rB.z + acc[pp][7]*rB.w;
        part += __shfl_xor(part, 1, 64);
        part += __shfl_xor(part, 2, 64);
        part += __shfl_xor(part, 4, 64);
        part += __shfl_xor(part, 8, 64);
        if (tx == 0 && s_b[p] >= 0) out[s_b[p]] = part;
    }
}

extern "C" void kernel_launch(void* const* d_in, const int* in_sizes, int n_in,
                              void* d_out, int out_size, void* d_ws, size_t ws_size,
                              hipStream_t stream) {
    const float* feats = (const float*)d_in[0];
    const float* fc_w  = (const float*)d_in[1];
    const float* fc_b  = (const float*)d_in[2];
    const float* w0    = (const float*)d_in[3];
    const float* al0   = (const float*)d_in[4];
    const float* ar0   = (const float*)d_in[5];
    const float* b0    = (const float*)d_in[6];
    const float* eemb0 = (const float*)d_in[7];
    const float* fce_w0= (const float*)d_in[8];
    const float* fce_b0= (const float*)d_in[9];
    const float* ae0   = (const float*)d_in[10];
    const float* w1    = (const float*)d_in[11];
    const float* al1   = (const float*)d_in[12];
    const float* ar1   = (const float*)d_in[13];
    const float* b1    = (const float*)d_in[14];
    const float* eemb1 = (const float*)d_in[15];
    const float* fce_w1= (const float*)d_in[16];
    const float* fce_b1= (const float*)d_in[17];
    const float* ae1   = (const float*)d_in[18];
    const float* w2    = (const float*)d_in[19];
    const float* al2   = (const float*)d_in[20];
    const float* ar2   = (const float*)d_in[21];
    const float* b2    = (const float*)d_in[22];
    const float* eemb2 = (const float*)d_in[23];
    const float* fce_w2= (const float*)d_in[24];
    const float* fce_b2= (const float*)d_in[25];
    const float* ae2   = (const float*)d_in[26];
    const float* resw2 = (const float*)d_in[27];
    const float* Wdm   = (const float*)d_in[28];
    const int* src   = (const int*)d_in[29];
    const int* dst   = (const int*)d_in[30];
    const int* etype = (const int*)d_in[31];
    const int* left  = (const int*)d_in[32];
    const int* right = (const int*)d_in[33];
    const int* mid   = (const int*)d_in[34];
    float* out = (float*)d_out;

    char* ws = (char*)d_ws;
    size_t off = 0;
    auto alloc = [&](size_t bytes) -> void* {
        void* p = ws + off;
        off = (off + bytes + 255) & ~(size_t)255;
        return p;
    };
    float* z    = (float*)alloc((size_t)NN*128*4);
    float* fbuf = (float*)alloc((size_t)NN*192*4);   // f0 f32 / f1,f2 bf16 (reused)
    float* r0   = (float*)alloc((size_t)NN*192*4);
    float* r1   = (float*)alloc((size_t)NN*192*4);
    float* r2   = (float*)alloc((size_t)NN*96*4);
    float* el   = (float*)alloc((size_t)NN*2*4);
    float* er   = (float*)alloc((size_t)NN*2*4);
    float* a0b  = (float*)alloc((size_t)EE*2*4);
    int* rowptr = (int*)alloc((size_t)(NN+1)*4);
    int* eidx   = (int*)alloc((size_t)EE*4);
    int* degc   = (int*)alloc((size_t)NN*4);
    int* perm   = (int*)alloc((size_t)NT*64*4);
    int* bcnt   = (int*)alloc(8*4);
    int* bbase  = (int*)alloc(8*4);
    int* bcur   = (int*)alloc(8*4);
    float* cwb  = (float*)alloc((size_t)T_*4096*4);
    float* cbb  = (float*)alloc((size_t)T_*64*4);
    float* tab0 = (float*)alloc(256);
    float* tab1 = (float*)alloc(256);
    float* tab2 = (float*)alloc(256);
    unsigned short* fb16 = (unsigned short*)fbuf;

    // ---- CSR build (by dst) ----
    hipMemsetAsync(degc, 0, (size_t)NN*4, stream);
    k_deg<<<dim3(EE/256), dim3(256), 0, stream>>>(dst, degc);
    k_scan<<<dim3(1), dim3(1024), 0, stream>>>(degc, rowptr);
    hipMemsetAsync(degc, 0, (size_t)NN*4, stream);
    k_fill<<<dim3(EE/256), dim3(256), 0, stream>>>(dst, rowptr, degc, eidx);

    // ---- pair buckets by relation ----
    hipMemsetAsync(bcnt, 0, 8*4, stream);
    hipMemsetAsync(bcur, 0, 8*4, stream);
    hipMemsetAsync(perm, 0xFF, (size_t)NT*64*4, stream);
    k_bcnt<<<dim3((BB+255)/256), dim3(256), 0, stream>>>(mid, bcnt);
    k_bscan<<<dim3(1), dim3(1), 0, stream>>>(bcnt, bbase);
    k_bfill<<<dim3((BB+255)/256), dim3(256), 0, stream>>>(mid, bbase, bcur, perm);

    // ---- stage 0 ----
    k_combine<<<dim3(T_), dim3(256), 0, stream>>>(fc_w, fc_b, w0, cwb, cbb);
    k_ntz<<<dim3(TILEST, T_), dim3(256), 0, stream>>>(feats, fc_w, fc_b, z);
    k_tab<<<dim3(RR*2), dim3(64), 0, stream>>>(eemb0, fce_w0, fce_b0, ae0, 2, tab0);
    k_tab<<<dim3(RR*2), dim3(64), 0, stream>>>(eemb1, fce_w1, fce_b1, ae1, 2, tab1);
    k_tab<<<dim3(RR*1), dim3(64), 0, stream>>>(eemb2, fce_w2, fce_b2, ae2, 1, tab2);

    // ---- layer 0 (f32 gather) ----
    k_f0t<<<dim3(TILEST, T_), dim3(256), 0, stream>>>(feats, cwb, cbb, al0, ar0, fbuf, el, er);
    k_aggr<0,2><<<dim3(NN), dim3(192), 0, stream>>>(rowptr, eidx, src, etype, el, er, tab0,
                                                    fbuf, nullptr, a0b, nullptr, b0, r0, z, 32);

    // ---- layer 1 (bf16 gather) ----
    k_f1t<<<dim3(TILESN, T_), dim3(256), 0, stream>>>(r0, w1, fb16);
    k_el1<<<dim3((NN*64)/256), dim3(256), 0, stream>>>(fb16, al1, ar1, el, er);
    k_aggr<1,2><<<dim3(NN), dim3(192), 0, stream>>>(rowptr, eidx, src, etype, el, er, tab1,
                                                    fb16, a0b, nullptr, r0, b1, r1, z, 64);

    // ---- layer 2 (bf16 gather) ----
    k_f2t<<<dim3(TILESN, T_), dim3(256), 0, stream>>>(r1, w2, resw2, fb16, r2);
    k_el2<<<dim3((NN*64)/256), dim3(256), 0, stream>>>(fb16, al2, ar2, el, er);
    k_aggr<2,1><<<dim3(NN), dim3(192), 0, stream>>>(rowptr, eidx, src, etype, el, er, tab2,
                                                    fb16, nullptr, nullptr, r2, b2, nullptr, z, 96);

    // ---- DistMult ----
    k_dm5<<<dim3(NT), dim3(128), 0, stream>>>(z, Wdm, left, right, mid, perm, out);
}

// Round 11
// 796.914 us; speedup vs baseline: 1.1041x; 1.1041x over previous
//
#include <hip/hip_runtime.h>

#define T_ 3
#define NPER 20000
#define NN 60000
#define EE 480000
#define BB 200000
#define RR 5
#define NT 3130    // BB/64 + RR  (padded pair tiles)
#define TILESN 938 // ceil(NN/64)
#define TILEST 313 // ceil(NPER/64)

typedef __attribute__((ext_vector_type(8))) short bf16x8;
typedef __attribute__((ext_vector_type(4))) float f32x4;

__device__ inline float lrelu(float x){ return x > 0.f ? x : 0.2f*x; }
__device__ inline float eluf(float x){ return x > 0.f ? x : (__expf(x) - 1.f); }
__device__ inline void fma4(float4& a, float s, const float4 v){ a.x+=s*v.x; a.y+=s*v.y; a.z+=s*v.z; a.w+=s*v.w; }
// bf16 helpers (RNE pack; unpack is shift/mask)
__device__ inline unsigned f2bu(float f){
    unsigned u = __float_as_uint(f);
    u = u + 0x7FFFu + ((u >> 16) & 1u);
    return u >> 16;
}
__device__ inline unsigned short f2b(float f){ return (unsigned short)f2bu(f); }
__device__ inline float bs2f(unsigned short b){ return __uint_as_float(((unsigned)b) << 16); }
__device__ inline float b2lo(unsigned u){ return __uint_as_float(u << 16); }
__device__ inline float b2hi(unsigned u){ return __uint_as_float(u & 0xFFFF0000u); }

// ---- combine input-fc with layer0 weights: cw[t]=fcw[t]@w0[t] [64x64], cb[t]=fcb[t]@w0[t] ----
__global__ __launch_bounds__(256) void k_combine(const float* __restrict__ fcw,
        const float* __restrict__ fcb, const float* __restrict__ w0,
        float* __restrict__ cw, float* __restrict__ cb) {
    __shared__ float A[64*32];
    __shared__ float Bm[32*64];
    int t = blockIdx.x, tid = threadIdx.x;
    for (int e = tid; e < 2048; e += 256) { A[e] = fcw[t*2048 + e]; Bm[e] = w0[t*2048 + e]; }
    __syncthreads();
    for (int e = tid; e < 4096; e += 256) {
        int k = e >> 6, o = e & 63;
        float acc = 0.f;
        #pragma unroll
        for (int m = 0; m < 32; ++m) acc += A[k*32+m] * Bm[m*64+o];
        cw[t*4096 + e] = acc;
    }
    if (tid < 64) {
        float acc = 0.f;
        #pragma unroll
        for (int m = 0; m < 32; ++m) acc += fcb[t*32+m] * Bm[m*64+tid];
        cb[t*64 + tid] = acc;
    }
}

// ---- fused input-fc + emb0 ----
__global__ __launch_bounds__(256) void k_ntz(const float* __restrict__ feats,
        const float* __restrict__ fcw, const float* __restrict__ fcb,
        float* __restrict__ z) {
    __shared__ float Xs[64][65];
    __shared__ float Ws[64*32];
    __shared__ float nrS[64];
    int ty = blockIdx.y;
    int n0 = ty*NPER + blockIdx.x*64;
    int nmax = (ty+1)*NPER;
    int tid = threadIdx.x;
    for (int e = tid; e < 4096; e += 256) {
        int n = e >> 6, k = e & 63;
        int gn = n0 + n;
        Xs[n][k] = (gn < nmax) ? feats[(size_t)gn*64 + k] : 0.f;
    }
    for (int e = tid; e < 2048; e += 256) Ws[e] = fcw[ty*2048 + e];
    __syncthreads();
    int ix = tid & 15, iy = tid >> 4;
    float acc[4][2] = {};
    #pragma unroll 8
    for (int k = 0; k < 64; ++k) {
        float wa = Ws[k*32 + 2*iy], wb = Ws[k*32 + 2*iy + 1];
        #pragma unroll
        for (int p = 0; p < 4; ++p) {
            float x = Xs[ix*4+p][k];
            acc[p][0] += x*wa; acc[p][1] += x*wb;
        }
    }
    float ba = fcb[ty*32 + 2*iy], bb = fcb[ty*32 + 2*iy + 1];
    __syncthreads();
    #pragma unroll
    for (int p = 0; p < 4; ++p) {
        acc[p][0] += ba; acc[p][1] += bb;
        Xs[ix*4+p][2*iy] = acc[p][0]; Xs[ix*4+p][2*iy+1] = acc[p][1];
    }
    __syncthreads();
    if (tid < 64) {
        float ss = 0.f;
        #pragma unroll
        for (int c = 0; c < 32; ++c) { float v = Xs[tid][c]; ss += v*v; }
        nrS[tid] = 3.f * fmaxf(sqrtf(ss), 1e-12f);
    }
    __syncthreads();
    #pragma unroll
    for (int p = 0; p < 4; ++p) {
        int gn = n0 + ix*4 + p;
        if (gn < nmax) {
            float inv = 1.f / nrS[ix*4+p];
            z[(size_t)gn*128 + 2*iy]   = acc[p][0]*inv;
            z[(size_t)gn*128 + 2*iy+1] = acc[p][1]*inv;
        }
    }
}

// ---- layer0 feat (GEMM-tiled, f32 out) + el/er epilogue ----
__global__ __launch_bounds__(256) void k_f0t(const float* __restrict__ feats,
        const float* __restrict__ cw, const float* __restrict__ cb,
        const float* __restrict__ al, const float* __restrict__ ar,
        float* __restrict__ f0, float* __restrict__ el, float* __restrict__ er) {
    __shared__ float Xs[64][65];
    __shared__ float Ws[64*64];
    __shared__ float avec[2][32], rvec[2][32];
    int ty = blockIdx.y;
    int n0 = ty*NPER + blockIdx.x*64;
    int nmax = (ty+1)*NPER;
    int tid = threadIdx.x;
    for (int e = tid; e < 4096; e += 256) {
        int n = e >> 6, k = e & 63;
        int gn = n0 + n;
        Xs[n][k] = (gn < nmax) ? feats[(size_t)gn*64 + k] : 0.f;
        Ws[e] = cw[ty*4096 + e];
    }
    if (tid < 64) {
        avec[tid>>5][tid&31] = al[(tid>>5)*96 + ty*32 + (tid&31)];
        rvec[tid>>5][tid&31] = ar[(tid>>5)*96 + ty*32 + (tid&31)];
    }
    __syncthreads();
    int ix = tid & 15, iy = tid >> 4;
    float acc[4][4] = {};
    #pragma unroll 8
    for (int k = 0; k < 64; ++k) {
        float4 wv = *(const float4*)&Ws[k*64 + iy*4];
        #pragma unroll
        for (int p = 0; p < 4; ++p) {
            float x = Xs[ix*4+p][k];
            acc[p][0] += x*wv.x; acc[p][1] += x*wv.y; acc[p][2] += x*wv.z; acc[p][3] += x*wv.w;
        }
    }
    float b0v = cb[ty*64 + iy*4], b1v = cb[ty*64 + iy*4+1], b2v = cb[ty*64 + iy*4+2], b3v = cb[ty*64 + iy*4+3];
    __syncthreads();
    #pragma unroll
    for (int p = 0; p < 4; ++p) {
        acc[p][0] += b0v; acc[p][1] += b1v; acc[p][2] += b2v; acc[p][3] += b3v;
        Xs[ix*4+p][iy*4]   = acc[p][0];
        Xs[ix*4+p][iy*4+1] = acc[p][1];
        Xs[ix*4+p][iy*4+2] = acc[p][2];
        Xs[ix*4+p][iy*4+3] = acc[p][3];
    }
    #pragma unroll
    for (int p = 0; p < 4; ++p) {
        int gn = n0 + ix*4 + p;
        if (gn < nmax)
            *(float4*)&f0[(size_t)gn*64 + iy*4] = make_float4(acc[p][0],acc[p][1],acc[p][2],acc[p][3]);
    }
    __syncthreads();
    if (tid < 128) {
        int n = tid >> 1, h = tid & 1;
        int gn = n0 + n;
        float pe = 0.f, pr = 0.f;
        #pragma unroll
        for (int d = 0; d < 32; ++d) {
            float v = Xs[n][h*32+d];
            pe += v*avec[h][d]; pr += v*rvec[h][d];
        }
        if (gn < nmax) { el[gn*2+h] = pe; er[gn*2+h] = pr; }
    }
}

// ---- layer1 feat (GEMM-tiled per slot t) -> bf16 out ----
__global__ __launch_bounds__(256) void k_f1t(const float* __restrict__ h1,
        const float* __restrict__ w1, unsigned short* __restrict__ f1) {
    __shared__ float Xs[64][65];
    __shared__ float Ws[64*64];
    int t = blockIdx.y;
    int n0 = blockIdx.x*64;
    int tid = threadIdx.x;
    for (int e = tid; e < 4096; e += 256) {
        int n = e >> 6, k = e & 63;
        int gn = n0 + n;
        Xs[n][k] = (gn < NN) ? h1[(size_t)gn*192 + (k>>5)*96 + t*32 + (k&31)] : 0.f;
        Ws[e] = w1[t*4096 + e];
    }
    __syncthreads();
    int ix = tid & 15, iy = tid >> 4;
    float acc[4][4] = {};
    #pragma unroll 8
    for (int k = 0; k < 64; ++k) {
        float4 wv = *(const float4*)&Ws[k*64 + iy*4];
        #pragma unroll
        for (int p = 0; p < 4; ++p) {
            float x = Xs[ix*4+p][k];
            acc[p][0] += x*wv.x; acc[p][1] += x*wv.y; acc[p][2] += x*wv.z; acc[p][3] += x*wv.w;
        }
    }
    int h = iy >> 3, dd = (iy & 7)*4;
    #pragma unroll
    for (int p = 0; p < 4; ++p) {
        int gn = n0 + ix*4 + p;
        if (gn < NN) {
            ushort4 o;
            o.x = f2b(acc[p][0]); o.y = f2b(acc[p][1]); o.z = f2b(acc[p][2]); o.w = f2b(acc[p][3]);
            *(ushort4*)&f1[(size_t)gn*192 + h*96 + t*32 + dd] = o;
        }
    }
}

// ---- layer2 feat (bf16) + residual (f32) ----
__global__ __launch_bounds__(256) void k_f2t(const float* __restrict__ h2,
        const float* __restrict__ w2, const float* __restrict__ rw,
        unsigned short* __restrict__ f2, float* __restrict__ rst2) {
    __shared__ float Xs[64][65];
    __shared__ float Ws[64*64];
    int t = blockIdx.y;
    int n0 = blockIdx.x*64;
    int tid = threadIdx.x;
    for (int e = tid; e < 4096; e += 256) {
        int n = e >> 6, k = e & 63;
        int gn = n0 + n;
        Xs[n][k] = (gn < NN) ? h2[(size_t)gn*192 + (k>>5)*96 + t*32 + (k&31)] : 0.f;
        int c = e & 63;
        Ws[e] = (c < 32) ? w2[t*2048 + n*32 + c] : rw[n*32 + (c-32)];
    }
    __syncthreads();
    int ix = tid & 15, iy = tid >> 4;
    float acc[4][4] = {};
    #pragma unroll 8
    for (int k = 0; k < 64; ++k) {
        float4 wv = *(const float4*)&Ws[k*64 + iy*4];
        #pragma unroll
        for (int p = 0; p < 4; ++p) {
            float x = Xs[ix*4+p][k];
            acc[p][0] += x*wv.x; acc[p][1] += x*wv.y; acc[p][2] += x*wv.z; acc[p][3] += x*wv.w;
        }
    }
    #pragma unroll
    for (int p = 0; p < 4; ++p) {
        int gn = n0 + ix*4 + p;
        if (gn < NN) {
            if (iy < 8) {
                ushort4 o;
                o.x = f2b(acc[p][0]); o.y = f2b(acc[p][1]); o.z = f2b(acc[p][2]); o.w = f2b(acc[p][3]);
                *(ushort4*)&f2[(size_t)gn*96 + t*32 + iy*4] = o;
            } else {
                *(float4*)&rst2[(size_t)gn*96 + t*32 + (iy-8)*4] = make_float4(acc[p][0],acc[p][1],acc[p][2],acc[p][3]);
            }
        }
    }
}

// ---- CSR build ----
__global__ void k_deg(const int* __restrict__ dst, int* __restrict__ deg) {
    int e = blockIdx.x*256 + threadIdx.x;
    if (e < EE) atomicAdd(&deg[dst[e]], 1);
}

__global__ __launch_bounds__(1024) void k_scan(const int* __restrict__ deg, int* __restrict__ rowptr) {
    __shared__ int sbase;
    __shared__ int wsum[16];
    int tid = threadIdx.x;
    if (tid == 0) sbase = 0;
    __syncthreads();
    for (int c0 = 0; c0 < NN; c0 += 1024) {
        int i = c0 + tid;
        int v = (i < NN) ? deg[i] : 0;
        int x = v;
        for (int d = 1; d < 64; d <<= 1) { int y = __shfl_up(x, d, 64); if ((tid & 63) >= d) x += y; }
        if ((tid & 63) == 63) wsum[tid >> 6] = x;
        __syncthreads();
        if (tid < 16) { int w = wsum[tid];
            for (int d = 1; d < 16; d <<= 1) { int y = __shfl_up(w, d, 64); if (tid >= d) w += y; }
            wsum[tid] = w; }
        __syncthreads();
        int woff = (tid >> 6) == 0 ? 0 : wsum[(tid >> 6) - 1];
        int incl = x + woff;
        if (i < NN) rowptr[i] = sbase + incl - v;
        __syncthreads();
        if (tid == 1023) sbase += incl;
        __syncthreads();
    }
    if (tid == 0) rowptr[NN] = sbase;
}

__global__ void k_fill(const int* __restrict__ dst, const int* __restrict__ rowptr,
                       int* __restrict__ cursor, int* __restrict__ eidx) {
    int e = blockIdx.x*256 + threadIdx.x;
    if (e >= EE) return;
    int d = dst[e];
    int pos = atomicAdd(&cursor[d], 1);
    eidx[rowptr[d] + pos] = e;
}

// ---- pair bucketing ----
__global__ __launch_bounds__(256) void k_bcnt(const int* __restrict__ mid, int* __restrict__ cnt) {
    __shared__ int h[RR];
    int tid = threadIdx.x, lane = tid & 63;
    if (tid < RR) h[tid] = 0;
    __syncthreads();
    int b = blockIdx.x*256 + tid;
    int r = (b < BB) ? mid[b] : -1;
    #pragma unroll
    for (int rr = 0; rr < RR; ++rr) {
        unsigned long long m = __ballot(r == rr);
        if (lane == 0 && m) atomicAdd(&h[rr], (int)__popcll(m));
    }
    __syncthreads();
    if (tid < RR && h[tid]) atomicAdd(&cnt[tid], h[tid]);
}

__global__ void k_bscan(const int* __restrict__ cnt, int* __restrict__ base) {
    base[0] = 0;
    for (int r = 0; r < RR; ++r) base[r+1] = base[r] + (((cnt[r] + 63) >> 6) << 6);
}

__global__ __launch_bounds__(256) void k_bfill(const int* __restrict__ mid, const int* __restrict__ base,
                        int* __restrict__ gcur, int* __restrict__ perm) {
    __shared__ int wcnt[4][RR];
    __shared__ int wbase[4][RR];
    __shared__ int bbase[RR];
    int tid = threadIdx.x, w = tid >> 6, lane = tid & 63;
    int b = blockIdx.x*256 + tid;
    int r = (b < BB) ? mid[b] : -1;
    int myrank = 0;
    #pragma unroll
    for (int rr = 0; rr < RR; ++rr) {
        unsigned long long m = __ballot(r == rr);
        if (r == rr) myrank = (int)__popcll(m & ((1ull << lane) - 1ull));
        if (lane == 0) wcnt[w][rr] = (int)__popcll(m);
    }
    __syncthreads();
    if (tid < RR) {
        int s = 0;
        #pragma unroll
        for (int ww = 0; ww < 4; ++ww) { wbase[ww][tid] = s; s += wcnt[ww][tid]; }
        bbase[tid] = s ? atomicAdd(&gcur[tid], s) : 0;
    }
    __syncthreads();
    if (r >= 0) perm[base[r] + bbase[r] + wbase[w][r] + myrank] = b;
}

// ---- edge logit table ----
__global__ void k_tab(const float* __restrict__ eemb, const float* __restrict__ fcw,
                      const float* __restrict__ fcb, const float* __restrict__ ae,
                      int H, float* __restrict__ tab) {
    int r = blockIdx.x / H, h = blockIdx.x % H, d = threadIdx.x;
    float acc = fcb[h*64+d];
    const float* er = eemb + r*64;
    #pragma unroll
    for (int k = 0; k < 64; ++k) acc += er[k] * fcw[k*(H*64) + h*64 + d];
    float v = acc * ae[h*64+d];
    for (int off = 32; off; off >>= 1) v += __shfl_xor(v, off, 64);
    if (d == 0) tab[r*H+h] = v;
}

// ---- fused per-node softmax + gather-aggregate + finalize ----
// MODE 0: H=2, f f32 [N,64] slot-compact; MODE 1: H=2, f bf16 [N,192]; MODE 2: H=1, f bf16 [N,96]
template<int MODE, int H>
__global__ __launch_bounds__(192) void k_aggr(
        const int* __restrict__ rowptr, const int* __restrict__ eidx,
        const int* __restrict__ src, const int* __restrict__ et,
        const float* __restrict__ el, const float* __restrict__ er,
        const float* __restrict__ tab, const void* __restrict__ fv,
        const float* __restrict__ resat, float* __restrict__ store0,
        const float* __restrict__ resid, const float* __restrict__ bias,
        float* __restrict__ outp, float* __restrict__ z, int zc) {
    constexpr int COLS  = (MODE==0) ? 64 : (MODE==1) ? 192 : 96;
    constexpr int PER   = (MODE==0) ? 4 : 8;
    constexpr int LANES = COLS/PER;           // 16 / 24 / 12
    constexpr int G     = 192/LANES;          // 12 / 8  / 16
    constexpr int RCOLS = (MODE==0) ? 192 : COLS;
    __shared__ float s_a[128][2];
    __shared__ int s_src[128];
    __shared__ int s_ts[128];
    __shared__ __align__(16) float red[G][RCOLS];
    __shared__ float hs[192];
    __shared__ float xs[96];
    __shared__ float part[2];
    int n = blockIdx.x, tid = threadIdx.x;
    int e0 = rowptr[n];
    int deg = rowptr[n+1] - e0;
    bool fast = (deg <= 128);
    float m0 = -1e30f, m1 = -1e30f, sum0 = 0.f, sum1 = 0.f;
    float er0 = 0.f, er1 = 0.f;
    if (tid < 64) {
        er0 = er[n*H];
        if (H == 2) er1 = er[n*H+1];
        if (fast) {
            int eA = 0, sA = 0, eB = 0, sB = 0;
            float xA0 = 0.f, xA1 = 0.f, xB0 = 0.f, xB1 = 0.f;
            bool hA = tid < deg, hB = tid + 64 < deg;
            if (hA) {
                eA = eidx[e0+tid]; sA = src[eA]; int rr = et[eA];
                xA0 = lrelu(el[sA*H] + er0 + tab[rr*H]);
                m0 = xA0;
                if (H == 2) { xA1 = lrelu(el[sA*H+1] + er1 + tab[rr*H+1]); m1 = xA1; }
            }
            if (hB) {
                eB = eidx[e0+tid+64]; sB = src[eB]; int rr = et[eB];
                xB0 = lrelu(el[sB*H] + er0 + tab[rr*H]);
                m0 = fmaxf(m0, xB0);
                if (H == 2) { xB1 = lrelu(el[sB*H+1] + er1 + tab[rr*H+1]); m1 = fmaxf(m1, xB1); }
            }
            for (int off = 32; off; off >>= 1) {
                m0 = fmaxf(m0, __shfl_xor(m0, off, 64));
                if (H == 2) m1 = fmaxf(m1, __shfl_xor(m1, off, 64));
            }
            float exA0 = 0.f, exA1 = 0.f, exB0 = 0.f, exB1 = 0.f;
            if (hA) { exA0 = __expf(xA0 - m0); sum0 += exA0;
                      if (H == 2) { exA1 = __expf(xA1 - m1); sum1 += exA1; } }
            if (hB) { exB0 = __expf(xB0 - m0); sum0 += exB0;
                      if (H == 2) { exB1 = __expf(xB1 - m1); sum1 += exB1; } }
            for (int off = 32; off; off >>= 1) {
                sum0 += __shfl_xor(sum0, off, 64);
                if (H == 2) sum1 += __shfl_xor(sum1, off, 64);
            }
            if (hA) {
                float a0 = exA0 / (sum0 + 1e-9f);
                if (MODE == 1) a0 = a0*0.95f + resat[eA*2]*0.05f;
                if (MODE == 0) store0[eA*2] = a0;
                s_a[tid][0] = a0;
                if (H == 2) {
                    float a1 = exA1 / (sum1 + 1e-9f);
                    if (MODE == 1) a1 = a1*0.95f + resat[eA*2+1]*0.05f;
                    if (MODE == 0) store0[eA*2+1] = a1;
                    s_a[tid][1] = a1;
                }
                s_src[tid] = sA;
                if (MODE == 0) s_ts[tid] = sA / NPER;
            }
            if (hB) {
                float a0 = exB0 / (sum0 + 1e-9f);
                if (MODE == 1) a0 = a0*0.95f + resat[eB*2]*0.05f;
                if (MODE == 0) store0[eB*2] = a0;
                s_a[tid+64][0] = a0;
                if (H == 2) {
                    float a1 = exB1 / (sum1 + 1e-9f);
                    if (MODE == 1) a1 = a1*0.95f + resat[eB*2+1]*0.05f;
                    if (MODE == 0) store0[eB*2+1] = a1;
                    s_a[tid+64][1] = a1;
                }
                s_src[tid+64] = sB;
                if (MODE == 0) s_ts[tid+64] = sB / NPER;
            }
        } else {
            for (int s2 = tid; s2 < deg; s2 += 64) {
                int e = eidx[e0+s2]; int sN = src[e]; int rr = et[e];
                float x0 = lrelu(el[sN*H] + er0 + tab[rr*H]);
                m0 = fmaxf(m0, x0);
                if (H == 2) { float x1 = lrelu(el[sN*H+1] + er1 + tab[rr*H+1]); m1 = fmaxf(m1, x1); }
            }
            for (int off = 32; off; off >>= 1) {
                m0 = fmaxf(m0, __shfl_xor(m0, off, 64));
                if (H == 2) m1 = fmaxf(m1, __shfl_xor(m1, off, 64));
            }
            for (int s2 = tid; s2 < deg; s2 += 64) {
                int e = eidx[e0+s2]; int sN = src[e]; int rr = et[e];
                float x0 = lrelu(el[sN*H] + er0 + tab[rr*H]);
                sum0 += __expf(x0 - m0);
                if (H == 2) { float x1 = lrelu(el[sN*H+1] + er1 + tab[rr*H+1]); sum1 += __expf(x1 - m1); }
            }
            for (int off = 32; off; off >>= 1) {
                sum0 += __shfl_xor(sum0, off, 64);
                if (H == 2) sum1 += __shfl_xor(sum1, off, 64);
            }
        }
    }
    float4 a0 = {0,0,0,0}, a1 = {0,0,0,0}, a2 = {0,0,0,0};
    int g = tid / LANES;
    int col = (tid - g*LANES)*PER;
    int hcol = (MODE==0) ? (col >> 5) : (MODE==1) ? (col / 96) : 0;
    for (int c0 = 0; c0 < deg; c0 += 128) {
        int cl = min(128, deg - c0);
        if (!fast && tid < 64) {
            for (int s2 = tid; s2 < cl; s2 += 64) {
                int e = eidx[e0+c0+s2]; int sN = src[e]; int rr = et[e];
                float x0 = lrelu(el[sN*H] + er0 + tab[rr*H]);
                float aa0 = __expf(x0 - m0) / (sum0 + 1e-9f);
                if (MODE == 1) aa0 = aa0*0.95f + resat[e*2]*0.05f;
                if (MODE == 0) store0[e*2] = aa0;
                s_a[s2][0] = aa0;
                if (H == 2) {
                    float x1 = lrelu(el[sN*H+1] + er1 + tab[rr*H+1]);
                    float aa1 = __expf(x1 - m1) / (sum1 + 1e-9f);
                    if (MODE == 1) aa1 = aa1*0.95f + resat[e*2+1]*0.05f;
                    if (MODE == 0) store0[e*2+1] = aa1;
                    s_a[s2][1] = aa1;
                }
                s_src[s2] = sN;
                if (MODE == 0) s_ts[s2] = sN / NPER;
            }
        }
        __syncthreads();
        if (MODE == 0) {
            const float* ff = (const float*)fv;
            for (int s2 = g; s2 < cl; s2 += G) {
                int sN = s_src[s2];
                float a = s_a[s2][hcol];
                float4 v = *(const float4*)&ff[(size_t)sN*64 + col];
                int ts = s_ts[s2];
                fma4(a0, (ts==0)?a:0.f, v);
                fma4(a1, (ts==1)?a:0.f, v);
                fma4(a2, (ts==2)?a:0.f, v);
            }
        } else {
            const unsigned short* fb = (const unsigned short*)fv;
            for (int s2 = g; s2 < cl; s2 += G) {
                int sN = s_src[s2];
                float a = s_a[s2][hcol];
                uint4 v = *(const uint4*)&fb[(size_t)sN*COLS + col];
                a0.x += a*b2lo(v.x); a0.y += a*b2hi(v.x);
                a0.z += a*b2lo(v.y); a0.w += a*b2hi(v.y);
                a1.x += a*b2lo(v.z); a1.y += a*b2hi(v.z);
                a1.z += a*b2lo(v.w); a1.w += a*b2hi(v.w);
            }
        }
        __syncthreads();
    }
    if (MODE == 0) {
        *(float4*)&red[g][col]       = a0;
        *(float4*)&red[g][64 + col]  = a1;
        *(float4*)&red[g][128 + col] = a2;
    } else {
        *(float4*)&red[g][col]     = a0;
        *(float4*)&red[g][col + 4] = a1;
    }
    __syncthreads();
    constexpr int FC = (MODE==2) ? 96 : 192;
    if (tid < FC) {
        int rc;
        if (MODE == 0) { int hh = tid/96, km = tid - hh*96, t = km>>5, d = km&31; rc = t*64 + hh*32 + d; }
        else rc = tid;
        float val = 0.f;
        #pragma unroll
        for (int gg = 0; gg < G; ++gg) val += red[gg][rc];
        if (MODE == 0) val = eluf(val + bias[tid]);
        if (MODE == 1) val = eluf(val + resid[(size_t)n*192 + tid] + bias[tid]);
        if (MODE == 2) val = val + resid[(size_t)n*96 + tid] + bias[tid];
        if (MODE < 2) outp[(size_t)n*192 + tid] = val;
        hs[tid] = val;
    }
    __syncthreads();
    float xx = 0.f;
    if (tid < 96) {
        float x = (MODE==2) ? hs[tid] : 0.5f*(hs[tid] + hs[96+tid]);
        xs[tid] = x;
        xx = x*x;
    }
    float s = xx;
    for (int off = 32; off; off >>= 1) s += __shfl_xor(s, off, 64);
    if ((tid & 63) == 0 && tid < 128) part[tid>>6] = s;
    __syncthreads();
    if (tid < 32) {
        float nr = 3.f * fmaxf(sqrtf(part[0] + part[1]), 1e-12f);
        z[(size_t)n*128 + zc + tid] = (xs[tid] + xs[32+tid] + xs[64+tid]) / nr;
    }
}

// ---- el/er for layer1 (bf16 f1) ----
__global__ void k_el1(const unsigned short* __restrict__ f1, const float* __restrict__ al,
                      const float* __restrict__ ar, float* __restrict__ el, float* __restrict__ er) {
    int gid = blockIdx.x*256 + threadIdx.x;
    int n = gid >> 6, l = gid & 63;
    if (n >= NN) return;
    const unsigned short* b = f1 + (size_t)n*192;
    float v0 = bs2f(b[l]), v1 = bs2f(b[l+64]), v2 = bs2f(b[l+128]);
    float pe0 = v0*al[l],     pr0 = v0*ar[l];
    float pe1 = v2*al[l+128], pr1 = v2*ar[l+128];
    float me = v1*al[l+64], mr = v1*ar[l+64];
    if (l < 32) { pe0 += me; pr0 += mr; } else { pe1 += me; pr1 += mr; }
    for (int off = 32; off; off >>= 1) {
        pe0 += __shfl_xor(pe0, off, 64); pr0 += __shfl_xor(pr0, off, 64);
        pe1 += __shfl_xor(pe1, off, 64); pr1 += __shfl_xor(pr1, off, 64);
    }
    if (l == 0) { el[n*2] = pe0; el[n*2+1] = pe1; er[n*2] = pr0; er[n*2+1] = pr1; }
}

// ---- el/er for layer2 (bf16 f2) ----
__global__ void k_el2(const unsigned short* __restrict__ f2, const float* __restrict__ al,
                      const float* __restrict__ ar, float* __restrict__ el, float* __restrict__ er) {
    int gid = blockIdx.x*256 + threadIdx.x;
    int n = gid >> 6, l = gid & 63;
    if (n >= NN) return;
    const unsigned short* b = f2 + (size_t)n*96;
    float v0 = bs2f(b[l]);
    float pe = v0*al[l], pr = v0*ar[l];
    if (l < 32) { float v1 = bs2f(b[64+l]); pe += v1*al[64+l]; pr += v1*ar[64+l]; }
    for (int off = 32; off; off >>= 1) { pe += __shfl_xor(pe, off, 64); pr += __shfl_xor(pr, off, 64); }
    if (l == 0) { el[n] = pe; er[n] = pr; }
}

// ---- DistMult v6: MFMA. C = le(64x128)@W(128x128) via mfma_f32_16x16x32_bf16, then rowdot ri ----
// 4 waves; wave w owns pairs w*16..w*16+15. A: row=lane&15, k=8*(lane>>4)+j. B: col=lane&15, same k.
// C/D: col=lane&15, row=4*(lane>>4)+reg (m89-verified).
__global__ __launch_bounds__(256) void k_dm6(const float* __restrict__ z, const float* __restrict__ W,
                       const int* __restrict__ left, const int* __restrict__ right,
                       const int* __restrict__ mid, const int* __restrict__ perm,
                       float* __restrict__ out) {
    __shared__ unsigned short le_s[64][136];   // [pair][k] bf16, row=272B (16B-mult)
    __shared__ unsigned short wt_s[128][136];  // [n][k] bf16 (W transposed), row=272B
    __shared__ int s_b[64], s_l[64], s_r[64];
    int tid = threadIdx.x;
    if (tid < 64) {
        int b = perm[blockIdx.x*64 + tid];
        s_b[tid] = b;
        s_l[tid] = (b >= 0) ? left[b]  : 0;
        s_r[tid] = (b >= 0) ? right[b] : 0;
    }
    __syncthreads();
    if (s_b[0] < 0) return;
    int r = mid[s_b[0]];
    // stage le bf16: i = p*64 + k2 (coalesced z reads; LDS u32 writes 2-way banked)
    for (int i = tid; i < 4096; i += 256) {
        int p = i >> 6, k2 = i & 63;
        const float* zp = z + (size_t)s_l[p]*128 + k2*2;
        *(unsigned*)&le_s[p][k2*2] = f2bu(zp[0]) | (f2bu(zp[1]) << 16);
    }
    // stage W transposed bf16: i = k2*128 + n (coalesced W reads of rows 2k2, 2k2+1)
    const float* Wp = W + (size_t)r*16384;
    for (int i = tid; i < 8192; i += 256) {
        int k2 = i >> 7, n = i & 127;
        unsigned lo = f2bu(Wp[(size_t)(2*k2)*128 + n]);
        unsigned hi = f2bu(Wp[(size_t)(2*k2+1)*128 + n]);
        *(unsigned*)&wt_s[n][k2*2] = lo | (hi << 16);
    }
    __syncthreads();
    int w = tid >> 6, lane = tid & 63;
    int lm = lane & 15, lk = lane >> 4;
    f32x4 acc[8] = {};
    #pragma unroll
    for (int k0 = 0; k0 < 128; k0 += 32) {
        bf16x8 af = *(const bf16x8*)&le_s[w*16 + lm][k0 + lk*8];
        #pragma unroll
        for (int t = 0; t < 8; ++t) {
            bf16x8 bfr = *(const bf16x8*)&wt_s[t*16 + lm][k0 + lk*8];
            acc[t] = __builtin_amdgcn_mfma_f32_16x16x32_bf16(af, bfr, acc[t], 0, 0, 0);
        }
    }
    // epilogue: out[p] = sum_n C[p][n]*ri[p][n]; lane holds col=t*16+lm, rows 4*lk+j
    #pragma unroll
    for (int j = 0; j < 4; ++j) {
        int row = lk*4 + j;
        int p = w*16 + row;
        const float* zr = z + (size_t)s_r[p]*128;
        float part = 0.f;
        #pragma unroll
        for (int t = 0; t < 8; ++t) part += acc[t][j] * zr[t*16 + lm];
        part += __shfl_xor(part, 1, 64);
        part += __shfl_xor(part, 2, 64);
        part += __shfl_xor(part, 4, 64);
        part += __shfl_xor(part, 8, 64);
        if (lm == 0 && s_b[p] >= 0) out[s_b[p]] = part;
    }
}

extern "C" void kernel_launch(void* const* d_in, const int* in_sizes, int n_in,
                              void* d_out, int out_size, void* d_ws, size_t ws_size,
                              hipStream_t stream) {
    const float* feats = (const float*)d_in[0];
    const float* fc_w  = (const float*)d_in[1];
    const float* fc_b  = (const float*)d_in[2];
    const float* w0    = (const float*)d_in[3];
    const float* al0   = (const float*)d_in[4];
    const float* ar0   = (const float*)d_in[5];
    const float* b0    = (const float*)d_in[6];
    const float* eemb0 = (const float*)d_in[7];
    const float* fce_w0= (const float*)d_in[8];
    const float* fce_b0= (const float*)d_in[9];
    const float* ae0   = (const float*)d_in[10];
    const float* w1    = (const float*)d_in[11];
    const float* al1   = (const float*)d_in[12];
    const float* ar1   = (const float*)d_in[13];
    const float* b1    = (const float*)d_in[14];
    const float* eemb1 = (const float*)d_in[15];
    const float* fce_w1= (const float*)d_in[16];
    const float* fce_b1= (const float*)d_in[17];
    const float* ae1   = (const float*)d_in[18];
    const float* w2    = (const float*)d_in[19];
    const float* al2   = (const float*)d_in[20];
    const float* ar2   = (const float*)d_in[21];
    const float* b2    = (const float*)d_in[22];
    const float* eemb2 = (const float*)d_in[23];
    const float* fce_w2= (const float*)d_in[24];
    const float* fce_b2= (const float*)d_in[25];
    const float* ae2   = (const float*)d_in[26];
    const float* resw2 = (const float*)d_in[27];
    const float* Wdm   = (const float*)d_in[28];
    const int* src   = (const int*)d_in[29];
    const int* dst   = (const int*)d_in[30];
    const int* etype = (const int*)d_in[31];
    const int* left  = (const int*)d_in[32];
    const int* right = (const int*)d_in[33];
    const int* mid   = (const int*)d_in[34];
    float* out = (float*)d_out;

    char* ws = (char*)d_ws;
    size_t off = 0;
    auto alloc = [&](size_t bytes) -> void* {
        void* p = ws + off;
        off = (off + bytes + 255) & ~(size_t)255;
        return p;
    };
    float* z    = (float*)alloc((size_t)NN*128*4);
    float* fbuf = (float*)alloc((size_t)NN*192*4);   // f0 f32 / f1,f2 bf16 (reused)
    float* r0   = (float*)alloc((size_t)NN*192*4);
    float* r1   = (float*)alloc((size_t)NN*192*4);
    float* r2   = (float*)alloc((size_t)NN*96*4);
    float* el   = (float*)alloc((size_t)NN*2*4);
    float* er   = (float*)alloc((size_t)NN*2*4);
    float* a0b  = (float*)alloc((size_t)EE*2*4);
    int* rowptr = (int*)alloc((size_t)(NN+1)*4);
    int* eidx   = (int*)alloc((size_t)EE*4);
    int* degc   = (int*)alloc((size_t)NN*4);
    int* perm   = (int*)alloc((size_t)NT*64*4);
    int* bcnt   = (int*)alloc(8*4);
    int* bbase  = (int*)alloc(8*4);
    int* bcur   = (int*)alloc(8*4);
    float* cwb  = (float*)alloc((size_t)T_*4096*4);
    float* cbb  = (float*)alloc((size_t)T_*64*4);
    float* tab0 = (float*)alloc(256);
    float* tab1 = (float*)alloc(256);
    float* tab2 = (float*)alloc(256);
    unsigned short* fb16 = (unsigned short*)fbuf;

    // ---- CSR build (by dst) ----
    hipMemsetAsync(degc, 0, (size_t)NN*4, stream);
    k_deg<<<dim3(EE/256), dim3(256), 0, stream>>>(dst, degc);
    k_scan<<<dim3(1), dim3(1024), 0, stream>>>(degc, rowptr);
    hipMemsetAsync(degc, 0, (size_t)NN*4, stream);
    k_fill<<<dim3(EE/256), dim3(256), 0, stream>>>(dst, rowptr, degc, eidx);

    // ---- pair buckets by relation ----
    hipMemsetAsync(bcnt, 0, 8*4, stream);
    hipMemsetAsync(bcur, 0, 8*4, stream);
    hipMemsetAsync(perm, 0xFF, (size_t)NT*64*4, stream);
    k_bcnt<<<dim3((BB+255)/256), dim3(256), 0, stream>>>(mid, bcnt);
    k_bscan<<<dim3(1), dim3(1), 0, stream>>>(bcnt, bbase);
    k_bfill<<<dim3((BB+255)/256), dim3(256), 0, stream>>>(mid, bbase, bcur, perm);

    // ---- stage 0 ----
    k_combine<<<dim3(T_), dim3(256), 0, stream>>>(fc_w, fc_b, w0, cwb, cbb);
    k_ntz<<<dim3(TILEST, T_), dim3(256), 0, stream>>>(feats, fc_w, fc_b, z);
    k_tab<<<dim3(RR*2), dim3(64), 0, stream>>>(eemb0, fce_w0, fce_b0, ae0, 2, tab0);
    k_tab<<<dim3(RR*2), dim3(64), 0, stream>>>(eemb1, fce_w1, fce_b1, ae1, 2, tab1);
    k_tab<<<dim3(RR*1), dim3(64), 0, stream>>>(eemb2, fce_w2, fce_b2, ae2, 1, tab2);

    // ---- layer 0 (f32 gather) ----
    k_f0t<<<dim3(TILEST, T_), dim3(256), 0, stream>>>(feats, cwb, cbb, al0, ar0, fbuf, el, er);
    k_aggr<0,2><<<dim3(NN), dim3(192), 0, stream>>>(rowptr, eidx, src, etype, el, er, tab0,
                                                    fbuf, nullptr, a0b, nullptr, b0, r0, z, 32);

    // ---- layer 1 (bf16 gather) ----
    k_f1t<<<dim3(TILESN, T_), dim3(256), 0, stream>>>(r0, w1, fb16);
    k_el1<<<dim3((NN*64)/256), dim3(256), 0, stream>>>(fb16, al1, ar1, el, er);
    k_aggr<1,2><<<dim3(NN), dim3(192), 0, stream>>>(rowptr, eidx, src, etype, el, er, tab1,
                                                    fb16, a0b, nullptr, r0, b1, r1, z, 64);

    // ---- layer 2 (bf16 gather) ----
    k_f2t<<<dim3(TILESN, T_), dim3(256), 0, stream>>>(r1, w2, resw2, fb16, r2);
    k_el2<<<dim3((NN*64)/256), dim3(256), 0, stream>>>(fb16, al2, ar2, el, er);
    k_aggr<2,1><<<dim3(NN), dim3(192), 0, stream>>>(rowptr, eidx, src, etype, el, er, tab2,
                                                    fb16, nullptr, nullptr, r2, b2, nullptr, z, 96);

    // ---- DistMult (MFMA) ----
    k_dm6<<<dim3(NT), dim3(256), 0, stream>>>(z, Wdm, left, right, mid, perm, out);
}